// Round 10
// baseline (116.259 us; speedup 1.0000x reference)
//
#include <hip/hip_runtime.h>

#define NQ  12
#define DIM 4096
#define TPB 256

typedef float v2f __attribute__((ext_vector_type(2)));
typedef float v4f __attribute__((ext_vector_type(4)));

// ---------------------------------------------------------------------------
// OCCUPANCY round: LDS 32768 -> 16384 B => 8 blocks/CU = 32 waves (HW max),
// up from 5 blocks/20 waves. The full-state buffer is replaced by chunked
// exchanges (same logical permutations as the measured-correct round-7 code):
//   E1 (bits 0-2 <-> 4-6, keep 3): wave-local, 2 chunks by (e3^e6) through a
//       4 KB/wave slab; chunk closure: P1 side regs r3=c^t2, P2 side regs
//       r'0^r'3=c. No barriers (same-wave DS program order, as rounds 7-9).
//   E2 (bits 3-5 <-> 7-9, keep 6): wave-local, 2 chunks by (e6^e9); P2 regs
//       r3=c^t5, P3 regs r'0^r'3=c.
//   E3 (bits 6-8 -> 9-11,0): cross-wave, 2 chunks by e9 through the full
//       16 KB buffer; 3 barriers (wc0|bar|rc0|bar|wc1|bar|rc1).
// Slot maps (s = free e-bits per chunk; byte = base + 8s, swizzle
// byte bits4-5 ^= bits7-8, E3 also bit6 ^= bit10). Bank check per 16-lane
// phase: E1w/E2w/E2r/E3w = min; E1r/E3r = 2-way (free, m136).
// Reg indices all compile-time (chunk-dependent reg halves via cndmask
// selects, not dynamic indexing -- avoids scratch).
// Kept from prior rounds: pk-asm gate math, rsqf, NT stores, replicated norm
// partials (one barrier), strided direct loads.
// ---------------------------------------------------------------------------

__device__ __forceinline__ float wave_reduce(float v) {
#pragma unroll
    for (int m = 32; m >= 1; m >>= 1) v += __shfl_xor(v, m, 64);
    return v;
}

#define BCAST(v, q) __uint_as_float(__builtin_amdgcn_readlane(__float_as_uint(v), (q)))

__device__ __forceinline__ v2f pk_add(v2f a, v2f b) {
    v2f d; asm("v_pk_add_f32 %0, %1, %2" : "=v"(d) : "v"(a), "v"(b)); return d;
}
__device__ __forceinline__ v2f pk_sub(v2f a, v2f b) {
    v2f d;
    asm("v_pk_add_f32 %0, %1, %2 neg_lo:[0,1] neg_hi:[0,1]" : "=v"(d) : "v"(a), "v"(b));
    return d;
}
__device__ __forceinline__ v2f pk_mul(v2f a, v2f b) {
    v2f d; asm("v_pk_mul_f32 %0, %1, %2" : "=v"(d) : "v"(a), "v"(b)); return d;
}
__device__ __forceinline__ v2f pk_mul_swap(v2f a, v2f b) {   // a * b.yx
    v2f d;
    asm("v_pk_mul_f32 %0, %1, %2 op_sel:[0,1] op_sel_hi:[1,0]" : "=v"(d) : "v"(a), "v"(b));
    return d;
}
__device__ __forceinline__ v2f pk_fma(v2f a, v2f b, v2f c) {
    v2f d; asm("v_pk_fma_f32 %0, %1, %2, %3" : "=v"(d) : "v"(a), "v"(b), "v"(c)); return d;
}

template <int MC, int MT, bool XGATE>
__device__ __forceinline__ void apply_layer(v2f* a, v2f ctv, v2f snv) {
#pragma unroll
    for (int i = 0; i < 16; ++i) {
        if (i & MC) continue;
        const int j = i | MC;
        const v2f t0 = a[i], t1 = a[j];
        a[i] = pk_add(t0, t1);
        a[j] = pk_sub(t0, t1);
    }
#pragma unroll
    for (int i = 0; i < 16; ++i) {
        if (!(i & MC) || (i & MT)) continue;
        const int j = i | MT;
        const v2f b0 = a[i], b1 = a[j];
        const v2f s0 = pk_mul_swap(snv, b0);
        const v2f s1 = pk_mul_swap(snv, b1);
        if (XGATE) { a[i] = pk_fma(ctv, b1, s0); a[j] = pk_fma(ctv, b0, s1); }
        else       { a[i] = pk_fma(ctv, b0, s1); a[j] = pk_fma(ctv, b1, s0); }
    }
}

__global__ __launch_bounds__(TPB, 8) void qlayer_kernel(
        const float* __restrict__ state, const float* __restrict__ params,
        float* __restrict__ out) {
    __shared__ __align__(16) v2f buf[2048];    // 16384 B -> 8 blocks/CU
    char* const lds = (char*)buf;

    const int t = threadIdx.x;
    const int lane = t & 63;
    const int wv = t >> 6;
    const long long sbase = (long long)blockIdx.x * DIM;

    const float th = params[lane < NQ ? lane : 0] * 0.5f;
    const float cl = cosf(th);
    const float sl = sinf(th);

    // ---- load 16 contiguous floats (64 B/thread) + norm ----
    const float4* gp = (const float4*)(state + sbase + t * 16);
    float4 xv[4];
    float ss = 0.f;
#pragma unroll
    for (int j = 0; j < 4; ++j) {
        const float4 v = gp[j];
        xv[j] = v;
        ss = fmaf(v.x, v.x, ss); ss = fmaf(v.y, v.y, ss);
        ss = fmaf(v.z, v.z, ss); ss = fmaf(v.w, v.w, ss);
    }
    ss = wave_reduce(ss);
    // replicate partials into each wave's 4 KB slab (round-8 pattern):
    // each wave reads only its OWN slab after bar1; its own E1 writes come
    // after the (data-dependent) reads -> no second barrier needed.
    if (lane == 0) {
#pragma unroll
        for (int s = 0; s < 4; ++s) *(float*)(lds + (s << 12) + (wv << 2)) = ss;
    }
    __syncthreads();                           // bar1
    const float* pr = (const float*)(lds + (wv << 12));
    const float invd = __builtin_amdgcn_rsqf(pr[0] + pr[1] + pr[2] + pr[3]);

    // ---- encoding ----
    v2f a[16];
#define ENC(k, xval)                                                      \
    {                                                                     \
        const float v   = (xval) * invd;                                  \
        const float re  = fminf(fmaxf(v, -1.0f), 1.0f);                   \
        const float imb = __builtin_amdgcn_sqrtf(fmaxf(1.0f - re * re, 0.f)); \
        const float im  = (v > 0.f) ? imb : ((v < 0.f) ? -imb : 0.f);     \
        v2f q; q.x = re; q.y = im;                                        \
        a[k] = q;                                                         \
    }
#pragma unroll
    for (int j = 0; j < 4; ++j) {
        const float4 xq = xv[j];
        ENC(4 * j + 0, xq.x); ENC(4 * j + 1, xq.y);
        ENC(4 * j + 2, xq.z); ENC(4 * j + 3, xq.w);
    }
#undef ENC

#define CTV(q) ({ v2f _c; _c.x = BCAST(cl, q); _c.y = _c.x; _c; })
#define SNV(q) ({ float _s = BCAST(sl, q); v2f _v; _v.x = _s; _v.y = -_s; _v; })

    // ---- pass 1: qubits 0-2 on e bits 0-3 (e = 16t + r) ----
    apply_layer<1, 2, true>(a, CTV(0), SNV(0));
    apply_layer<2, 4, true>(a, CTV(1), SNV(1));
    apply_layer<4, 8, true>(a, CTV(2), SNV(2));

    v2f b[16];
    // ---- E1: wave-local, 2 chunks by c = e3^e6. s = {e0-2 | e4-9} ----
    {
        const int B1w = ((wv << 12) | ((t & 63) << 6)) ^ (((t >> 1) & 3) << 4);
        const int B1r = (wv << 12) | ((t & 7) << 3) | (((t >> 3) & 7) << 9);
        const bool hs = ((t >> 2) & 1) != 0;   // h = c ^ t2
#pragma unroll
        for (int c = 0; c < 2; ++c) {
            const bool hi = hs ^ (c != 0);     // use a[8..15] half?
#pragma unroll
            for (int k = 0; k < 4; ++k) {
                const v2f lo = hi ? a[8 + 2 * k] : a[2 * k];
                const v2f h1 = hi ? a[9 + 2 * k] : a[2 * k + 1];
                v4f w; w.x = lo.x; w.y = lo.y; w.z = h1.x; w.w = h1.y;
                *(v4f*)(lds + (B1w ^ (k << 4))) = w;
            }
#pragma unroll
            for (int m = 0; m < 8; ++m) {
                const int rp = (m << 1) | (c ^ (m >> 2));          // compile-time
                const int C  = (m << 6) | (((m >> 1) & 3) << 4);
                b[rp] = *(const v2f*)(lds + (B1r ^ C));
            }
        }
    }

    // ---- pass 2: qubits 3-5 on e bits 3-6 ----
    apply_layer<1, 2, true>(b, CTV(3), SNV(3));
    apply_layer<2, 4, true>(b, CTV(4), SNV(4));
    apply_layer<4, 8, true>(b, CTV(5), SNV(5));

    // ---- E2: wave-local, 2 chunks by c = e6^e9. s = {e3-5 | e0-2 | e7-9} ----
    {
        const int B2w = ((wv << 12) | (((t >> 3) & 7) << 9) | ((t & 7) << 6))
                        ^ (((t >> 1) & 3) << 4);
        const int B2r = ((wv << 12) | ((t & 7) << 6) | (((t >> 3) & 7) << 3))
                        ^ (((t >> 1) & 3) << 4);
        const bool hs = ((t >> 5) & 1) != 0;   // h = c ^ t5
#pragma unroll
        for (int c = 0; c < 2; ++c) {
            const bool hi = hs ^ (c != 0);
#pragma unroll
            for (int k = 0; k < 4; ++k) {
                const v2f lo = hi ? b[8 + 2 * k] : b[2 * k];
                const v2f h1 = hi ? b[9 + 2 * k] : b[2 * k + 1];
                v4f w; w.x = lo.x; w.y = lo.y; w.z = h1.x; w.w = h1.y;
                *(v4f*)(lds + (B2w ^ (k << 4))) = w;
            }
#pragma unroll
            for (int m = 0; m < 8; ++m) {
                const int rp = (m << 1) | (c ^ (m >> 2));
                a[rp] = *(const v2f*)(lds + B2r + (m << 9));
            }
        }
    }

    // ---- pass 3: qubits 6-8 on e bits 6-9 ----
    apply_layer<1, 2, true>(a, CTV(6), SNV(6));
    apply_layer<2, 4, true>(a, CTV(7), SNV(7));
    apply_layer<4, 8, true>(a, CTV(8), SNV(8));

    // ---- E3: cross-wave, 2 chunks by c = e9. s = {e6-8 | e0-5 | e10-11} ----
    {
        const int B3w = (((t & 63) << 6) | (wv << 12))
                        ^ (((t >> 1) & 3) << 4) ^ (((t >> 4) & 1) << 6);
        const int B4r = ((((t >> 5) & 7) << 3) | ((t & 31) << 7))
                        ^ ((t & 3) << 4) ^ (((t >> 3) & 1) << 6);
        // chunk 0: writes a[0..7] (r3 = 0)
#pragma unroll
        for (int k = 0; k < 4; ++k) {
            v4f w; w.x = a[2 * k].x; w.y = a[2 * k].y;
            w.z = a[2 * k + 1].x; w.w = a[2 * k + 1].y;
            *(v4f*)(lds + (B3w ^ (k << 4))) = w;
        }
        __syncthreads();                       // c0 writes visible
#pragma unroll
        for (int j = 0; j < 4; ++j) {
            b[(j << 1)]     = *(const v2f*)(lds + (B4r + (j << 12)));
            b[(j << 1) | 8] = *(const v2f*)(lds + ((B4r ^ 64) + (j << 12)));
        }
        __syncthreads();                       // c0 reads done
        // chunk 1: writes a[8..15] (r3 = 1)
#pragma unroll
        for (int k = 0; k < 4; ++k) {
            v4f w; w.x = a[8 + 2 * k].x; w.y = a[8 + 2 * k].y;
            w.z = a[9 + 2 * k].x; w.w = a[9 + 2 * k].y;
            *(v4f*)(lds + (B3w ^ (k << 4))) = w;
        }
        __syncthreads();                       // c1 writes visible
#pragma unroll
        for (int j = 0; j < 4; ++j) {
            b[(j << 1) | 1]     = *(const v2f*)(lds + (B4r + (j << 12)));
            b[(j << 1) | 1 | 8] = *(const v2f*)(lds + ((B4r ^ 64) + (j << 12)));
        }
    }

    // ---- pass 4: qubits 9-11 on reg bits 0-2 = e9-11, bit 3 = e0 ----
    apply_layer<1, 2, true >(b, CTV(9),  SNV(9));
    apply_layer<2, 4, true >(b, CTV(10), SNV(10));
    apply_layer<4, 8, false>(b, CTV(11), SNV(11));

    // probs epilogue; scale = 1/4096 * (1/sqrt2)^24 = 2^-24; NT stores.
    {
        v2f sc2; sc2.x = 0x1p-24f; sc2.y = 0x1p-24f;
        v2f* outp = (v2f*)(out + sbase);
#pragma unroll
        for (int k = 0; k < 8; ++k) {
            const v2f q0 = pk_mul(b[k], b[k]);
            const v2f q1 = pk_mul(b[k | 8], b[k | 8]);
            v2f res; res.x = q0.x + q0.y;
            res.y = q1.x + q1.y;
            res = pk_mul(res, sc2);
            __builtin_nontemporal_store(res, outp + t + (k << 8));
        }
    }
#undef CTV
#undef SNV
}

extern "C" void kernel_launch(void* const* d_in, const int* in_sizes, int n_in,
                              void* d_out, int out_size, void* d_ws, size_t ws_size,
                              hipStream_t stream) {
    (void)in_sizes; (void)n_in; (void)out_size; (void)d_ws; (void)ws_size;
    const float* state  = (const float*)d_in[0];   // (8,512,4096) fp32
    const float* params = (const float*)d_in[1];   // (12,) fp32
    float* out = (float*)d_out;                    // (8,512,4096) fp32
    qlayer_kernel<<<dim3(4096), dim3(TPB), 0, stream>>>(state, params, out);
}